// Round 2
// baseline (92.701 us; speedup 1.0000x reference)
//
#include <hip/hip_runtime.h>

// score[e] = dot(h[u[e]], h[v[e]]), h: [N_NODES, 128] f32, u/v: [N_EDGES] i32
// 32 lanes per edge (1 float4 per row per lane), 4 edges per group-iteration
// for memory-level parallelism: 8 index loads + 8 row loads in flight per
// 32-lane group before any consumption.

constexpr int D_FEAT = 128;

__global__ __launch_bounds__(256) void edge_dot_kernel(
    const float* __restrict__ h,
    const int* __restrict__ u,
    const int* __restrict__ v,
    float* __restrict__ out,
    int n_edges)
{
    const int tid      = blockIdx.x * blockDim.x + threadIdx.x;
    const int sub      = threadIdx.x & 31;          // lane within 32-lane group
    const int group    = tid >> 5;                  // 32-lane group id
    const int n_groups = (gridDim.x * blockDim.x) >> 5;

    constexpr int EPT = 4;                          // edges per group per iter

    for (int base = group * EPT; base < n_edges; base += n_groups * EPT) {
        int iu[EPT], iv[EPT];
        #pragma unroll
        for (int i = 0; i < EPT; ++i) {
            int ei = base + i;
            ei = ei < n_edges ? ei : n_edges - 1;   // clamp for tail safety
            iu[i] = u[ei];
            iv[i] = v[ei];
        }

        float4 A[EPT], B[EPT];
        #pragma unroll
        for (int i = 0; i < EPT; ++i)
            A[i] = *reinterpret_cast<const float4*>(h + (size_t)iu[i] * D_FEAT + sub * 4);
        #pragma unroll
        for (int i = 0; i < EPT; ++i)
            B[i] = *reinterpret_cast<const float4*>(h + (size_t)iv[i] * D_FEAT + sub * 4);

        float r[EPT];
        #pragma unroll
        for (int i = 0; i < EPT; ++i) {
            float acc = A[i].x * B[i].x + A[i].y * B[i].y
                      + A[i].z * B[i].z + A[i].w * B[i].w;
            // reduce across the 32-lane group (masks < 32 stay in the group)
            acc += __shfl_xor(acc, 16, 64);
            acc += __shfl_xor(acc, 8, 64);
            acc += __shfl_xor(acc, 4, 64);
            acc += __shfl_xor(acc, 2, 64);
            acc += __shfl_xor(acc, 1, 64);
            r[i] = acc;
        }

        // All EPT results are valid in lane 0; base is a multiple of 4.
        if (sub == 0) {
            if (base + EPT <= n_edges) {
                float4 o = make_float4(r[0], r[1], r[2], r[3]);
                *reinterpret_cast<float4*>(out + base) = o;
            } else {
                for (int i = 0; i < EPT; ++i)
                    if (base + i < n_edges) out[base + i] = r[i];
            }
        }
    }
}

extern "C" void kernel_launch(void* const* d_in, const int* in_sizes, int n_in,
                              void* d_out, int out_size, void* d_ws, size_t ws_size,
                              hipStream_t stream) {
    const float* h = (const float*)d_in[0];
    const int*   u = (const int*)d_in[1];
    const int*   v = (const int*)d_in[2];
    float* out = (float*)d_out;

    const int n_edges = in_sizes[1];

    const int block = 256;
    const int grid  = 2048;   // 16384 groups of 32 lanes; 65536 edges per pass

    edge_dot_kernel<<<grid, block, 0, stream>>>(h, u, v, out, n_edges);
}